// Round 5
// baseline (323.514 us; speedup 1.0000x reference)
//
#include <hip/hip_runtime.h>

// MyCrossAttention fused kernel for MI355X (gfx950), round 5.
// B=4, C=128, T=400, F=64, H=4, HID=CV=32, N=B*T=1600.
// One block per n; 8 waves (512 thr) as 4x2 grid over [128 rows][128 cols=s*64+f].
// vs round 3 (passing): + LDS-staged coalesced output stores (round-4 fix),
// + split-precision weights (W = W_hi + W_lo, 2 MFMA passes  -> no weight rounding),
// + fp32 V kept in registers through the attention mix (single bf16 rounding).

typedef short s8v __attribute__((ext_vector_type(8)));   // 8 bf16 bits
typedef float f4v __attribute__((ext_vector_type(4)));   // MFMA accumulator

__device__ __forceinline__ unsigned short f2bf(float x){
  unsigned u = __float_as_uint(x);
  return (unsigned short)((u + 0x7FFFu + ((u >> 16) & 1u)) >> 16);  // RNE
}
__device__ __forceinline__ float b2f(unsigned short b){
  return __uint_as_float(((unsigned)b) << 16);
}
__device__ __forceinline__ float wred(float v){
  #pragma unroll
  for (int off = 32; off; off >>= 1) v += __shfl_xor(v, off, 64);
  return v;
}

// ---------------- prep: W -> (hi, lo) bf16 pair; (g,z) packed bf16 [r][f] ----------------
// ws layout: Wb_hi 4x16384 shorts | Wb_lo 4x16384 shorts | GZ 4x8192 u32
__global__ __launch_bounds__(256)
void prep_k(const float* __restrict__ Wq, const float* __restrict__ Wk,
            const float* __restrict__ Wv, const float* __restrict__ Wo,
            const float* __restrict__ gq, const float* __restrict__ zq,
            const float* __restrict__ gk, const float* __restrict__ zk,
            const float* __restrict__ gv, const float* __restrict__ zv,
            const float* __restrict__ go, const float* __restrict__ zo,
            unsigned short* __restrict__ Wb, unsigned* __restrict__ GZ)
{
  int t = blockIdx.x * 256 + threadIdx.x;
  if (t < 65536) {                       // 4 x [128][128] weight matrices
    int sel = t >> 14, i = t & 16383;
    const float* s = sel == 0 ? Wq : sel == 1 ? Wk : sel == 2 ? Wv : Wo;
    float w = s[i];
    unsigned short hi = f2bf(w);
    Wb[t]         = hi;
    Wb[65536 + t] = f2bf(w - b2f(hi));   // lo residue
  } else {                               // 4 x [128][64] packed (g,z)
    int u = t - 65536;
    int sel = u >> 13, i = u & 8191;
    const float* g = sel == 0 ? gq : sel == 1 ? gk : sel == 2 ? gv : go;
    const float* z = sel == 0 ? zq : sel == 1 ? zk : sel == 2 ? zv : zo;
    GZ[u] = (unsigned)f2bf(g[i]) | ((unsigned)f2bf(z[i]) << 16);
  }
}

// ---------------- 32x64x128 GEMM tile: acc = (A_hi + A_lo)(global bf16) * B(LDS swizzled) ----------------
__device__ __forceinline__ void gemm_tile(const unsigned short* __restrict__ A,  // hi; lo at +65536
                                          const unsigned short* __restrict__ Bl,
                                          int m0, int n0, int row16, int q4,
                                          f4v acc[2][4])
{
  const unsigned short* Al = A + 65536;
  #pragma unroll
  for (int mi = 0; mi < 2; ++mi)
    #pragma unroll
    for (int ni = 0; ni < 4; ++ni)
      acc[mi][ni] = (f4v){0.f, 0.f, 0.f, 0.f};

  #pragma unroll
  for (int kk = 0; kk < 4; ++kk) {
    s8v ah[2], al[2];
    #pragma unroll
    for (int mi = 0; mi < 2; ++mi) {
      int off = (m0 + mi*16 + row16)*128 + kk*32 + q4*8;
      ah[mi] = *(const s8v*)(A  + off);
      al[mi] = *(const s8v*)(Al + off);
    }
    #pragma unroll
    for (int ni = 0; ni < 4; ++ni) {
      int rw = n0 + ni*16 + row16;
      const s8v b = *(const s8v*)(Bl + rw*128 + ((kk*32 + q4*8) ^ ((rw & 7) << 3)));
      #pragma unroll
      for (int mi = 0; mi < 2; ++mi) {
        acc[mi][ni] = __builtin_amdgcn_mfma_f32_16x16x32_bf16(ah[mi], b, acc[mi][ni], 0, 0, 0);
        acc[mi][ni] = __builtin_amdgcn_mfma_f32_16x16x32_bf16(al[mi], b, acc[mi][ni], 0, 0, 0);
      }
    }
  }
}

// ---------------- QKV epilogue: bias + PReLU + LN(2048 = wave tile) + g/z (scalar) ----------------
__device__ __forceinline__ void qkv_epi(f4v acc[2][4],
                                        const float* __restrict__ bias,
                                        float p,
                                        const unsigned* __restrict__ GZb,  // [r][f]
                                        unsigned short* __restrict__ Lout, bool keep,
                                        int m0, int n0, int row16, int q4)
{
  float sum = 0.f, sq = 0.f;
  #pragma unroll
  for (int mi = 0; mi < 2; ++mi) {
    #pragma unroll
    for (int j = 0; j < 4; ++j) {
      float bb = bias[m0 + mi*16 + q4*4 + j];
      #pragma unroll
      for (int ni = 0; ni < 4; ++ni) {
        float v = acc[mi][ni][j] + bb;
        v = v >= 0.f ? v : p * v;
        acc[mi][ni][j] = v;
        sum += v; sq += v*v;
      }
    }
  }
  sum = wred(sum); sq = wred(sq);
  float mu = sum * (1.f/2048.f);
  float rs = rsqrtf(sq * (1.f/2048.f) - mu*mu + 1e-5f);
  #pragma unroll
  for (int mi = 0; mi < 2; ++mi) {
    #pragma unroll
    for (int ni = 0; ni < 4; ++ni) {
      int f   = ni*16 + row16;
      int col = n0 + f;
      int sw  = (col & 7) << 3;
      #pragma unroll
      for (int j = 0; j < 4; ++j) {
        int r = m0 + mi*16 + q4*4 + j;
        unsigned gz = GZb[r*64 + f];
        float g = b2f((unsigned short)(gz & 0xffffu));
        float z = b2f((unsigned short)(gz >> 16));
        float vn = (acc[mi][ni][j] - mu) * rs * g + z;
        if (keep) acc[mi][ni][j] = vn;
        else      Lout[col*128 + (r ^ sw)] = f2bf(vn);
      }
    }
  }
}

// ---------------- main fused kernel ----------------
__global__ __launch_bounds__(512, 4)
void fused_k(const float* __restrict__ x1, const float* __restrict__ x2,
             const unsigned short* __restrict__ Wb, const unsigned* __restrict__ GZ,
             const float* __restrict__ bq, const float* __restrict__ bk,
             const float* __restrict__ bv, const float* __restrict__ bo,
             const float* __restrict__ pq, const float* __restrict__ pk,
             const float* __restrict__ pv, const float* __restrict__ po,
             float* __restrict__ out)
{
  __shared__ __align__(16) unsigned short Xl[16384];  // x, [rw=s*64+f][c], swizzled
  __shared__ __align__(16) unsigned short Kl[16384];  // K bf16 -> V f32 -> mix bf16 -> y f32 stage
  __shared__ float sc[16];              // raw scores [h][s][t]
  __shared__ float lnb[16];             // out-LN cross-wave partials

  const int n   = blockIdx.x;
  const int bI  = n / 400, tI = n % 400;
  const int tid = threadIdx.x;
  const int lane = tid & 63, wave = tid >> 6;
  const int wm = wave >> 1, wn = wave & 1;     // wm = head (rows), wn = stream (cols)
  const int m0 = wm * 32, n0 = wn * 64;
  const int row16 = lane & 15, q4 = lane >> 4;

  // ---- phase 1: load x -> Xl (bf16, transposed, swizzled) ----
  {
    int c = tid & 127, s = (tid >> 7) & 1, half = tid >> 8;
    const float* src = (s ? x2 : x1) + ((size_t)(bI*128 + c)*400 + tI)*64 + half*32;
    #pragma unroll
    for (int j = 0; j < 8; ++j) {
      float4 v = ((const float4*)src)[j];
      int f0 = half*32 + j*4;
      float vv[4] = {v.x, v.y, v.z, v.w};
      #pragma unroll
      for (int e = 0; e < 4; ++e) {
        int rw = s*64 + f0 + e;
        Xl[rw*128 + (c ^ ((rw & 7) << 3))] = f2bf(vv[e]);
      }
    }
  }
  __syncthreads();

  f4v acc[2][4];

  // ---- phase 2: K branch -> Kl (bf16) ----
  gemm_tile(Wb + 16384*1, Xl, m0, n0, row16, q4, acc);
  qkv_epi(acc, bk, pk[wm], GZ + 8192*1, Kl, false, m0, n0, row16, q4);
  __syncthreads();

  // ---- phase 3: Q branch (kept in regs fp32) + scores ----
  gemm_tile(Wb + 16384*0, Xl, m0, n0, row16, q4, acc);
  qkv_epi(acc, bq, pq[wm], GZ + 8192*0, Kl, true, m0, n0, row16, q4);
  {
    float p0 = 0.f, p1 = 0.f;   // scores vs K stream t=0,1 for (h=wm, s=wn)
    #pragma unroll
    for (int mi = 0; mi < 2; ++mi) {
      #pragma unroll
      for (int ni = 0; ni < 4; ++ni) {
        int f  = ni*16 + row16;
        int sw = (f & 7) << 3;      // (64+f)&7 == f&7
        #pragma unroll
        for (int j = 0; j < 4; ++j) {
          int r = m0 + mi*16 + q4*4 + j;
          float qv = acc[mi][ni][j];
          float k0 = b2f(Kl[f*128      + (r ^ sw)]);
          float k1 = b2f(Kl[(64+f)*128 + (r ^ sw)]);
          p0 += qv * k0;
          p1 += qv * k1;
        }
      }
    }
    p0 = wred(p0); p1 = wred(p1);
    if (lane == 0) {
      sc[wm*4 + wn*2 + 0] = p0;
      sc[wm*4 + wn*2 + 1] = p1;
    }
  }
  __syncthreads();   // K reads done; Kl reusable

  // ---- phase 4: V branch, fp32 in regs ----
  gemm_tile(Wb + 16384*2, Xl, m0, n0, row16, q4, acc);
  qkv_epi(acc, bv, pv[wm], GZ + 8192*2, Kl, true, m0, n0, row16, q4);  // keep fp32

  // ---- phase 5: fp32 attention mix (pairwise wave exchange), single bf16 rounding ----
  {
    float* KlF = (float*)Kl;     // [c=128][f=64] fp32 = 32 KB
    if (wn == 0) {               // publish V(t=0) fp32
      #pragma unroll
      for (int mi = 0; mi < 2; ++mi)
        #pragma unroll
        for (int ni = 0; ni < 4; ++ni) {
          int f = ni*16 + row16;
          #pragma unroll
          for (int j = 0; j < 4; ++j)
            KlF[(m0 + mi*16 + q4*4 + j)*64 + f] = acc[mi][ni][j];
        }
    }
    __syncthreads();
    float v0r[2][4][4];
    if (wn == 1) {               // read V(t=0); own acc = V(t=1), same (c,f) positions
      #pragma unroll
      for (int mi = 0; mi < 2; ++mi)
        #pragma unroll
        for (int ni = 0; ni < 4; ++ni) {
          int f = ni*16 + row16;
          #pragma unroll
          for (int j = 0; j < 4; ++j)
            v0r[mi][ni][j] = KlF[(m0 + mi*16 + q4*4 + j)*64 + f];
        }
    }
    __syncthreads();             // all reads done before mix overwrites Kl
    if (wn == 1) {
      const float is = 0.02209708691f;  // 1/sqrt(2048)
      float s00 = sc[wm*4+0]*is, s01 = sc[wm*4+1]*is;   // s=0: t=0,1
      float s10 = sc[wm*4+2]*is, s11 = sc[wm*4+3]*is;   // s=1: t=0,1
      float mA = fmaxf(s00, s01), e0 = __expf(s00-mA), e1 = __expf(s01-mA);
      float a00 = e0/(e0+e1), a01 = e1/(e0+e1);
      float mB = fmaxf(s10, s11), e2 = __expf(s10-mB), e3 = __expf(s11-mB);
      float a10 = e2/(e2+e3), a11 = e3/(e2+e3);
      #pragma unroll
      for (int mi = 0; mi < 2; ++mi)
        #pragma unroll
        for (int ni = 0; ni < 4; ++ni) {
          int f  = ni*16 + row16;
          int sw = (f & 7) << 3;
          #pragma unroll
          for (int j = 0; j < 4; ++j) {
            int c = m0 + mi*16 + q4*4 + j;
            float v0 = v0r[mi][ni][j], v1 = acc[mi][ni][j];
            Kl[f*128      + (c ^ sw)] = f2bf(a00*v0 + a01*v1);   // mix, stream 0
            Kl[(64+f)*128 + (c ^ sw)] = f2bf(a10*v0 + a11*v1);   // mix, stream 1
          }
        }
    }
    __syncthreads();
  }

  // ---- phase 6: output projection + LN(8192 per stream) + g/z + residual ----
  gemm_tile(Wb + 16384*3, Kl, m0, n0, row16, q4, acc);
  {
    float pov = po[0];
    float sum = 0.f, sq = 0.f;
    #pragma unroll
    for (int mi = 0; mi < 2; ++mi) {
      #pragma unroll
      for (int j = 0; j < 4; ++j) {
        float bb = bo[m0 + mi*16 + q4*4 + j];
        #pragma unroll
        for (int ni = 0; ni < 4; ++ni) {
          float v = acc[mi][ni][j] + bb;
          v = v >= 0.f ? v : pov * v;
          acc[mi][ni][j] = v;
          sum += v; sq += v*v;
        }
      }
    }
    sum = wred(sum); sq = wred(sq);
    if (lane == 0) { lnb[wave] = sum; lnb[8 + wave] = sq; }
    __syncthreads();   // also: all phase-6 gemm reads of Kl complete
    float tot  = lnb[wn]   + lnb[wn+2]   + lnb[wn+4]   + lnb[wn+6];
    float totq = lnb[8+wn] + lnb[8+wn+2] + lnb[8+wn+4] + lnb[8+wn+6];
    float mu = tot * (1.f/8192.f);
    float rs = rsqrtf(totq * (1.f/8192.f) - mu*mu + 1e-5f);
    const unsigned* GZo = GZ + 8192*3;
    #pragma unroll
    for (int mi = 0; mi < 2; ++mi) {
      #pragma unroll
      for (int ni = 0; ni < 4; ++ni) {
        int f   = ni*16 + row16;
        int col = n0 + f;
        int sw  = (col & 7) << 3;
        #pragma unroll
        for (int j = 0; j < 4; ++j) {
          int r = m0 + mi*16 + q4*4 + j;
          unsigned gz = GZo[r*64 + f];
          float g = b2f((unsigned short)(gz & 0xffffu));
          float z = b2f((unsigned short)(gz >> 16));
          float y  = (acc[mi][ni][j] - mu) * rs * g + z;
          float xv = b2f(Xl[col*128 + (r ^ sw)]);   // residual (bf16-rounded x)
          acc[mi][ni][j] = y + xv;
        }
      }
    }
  }

  // ---- phase 7: stage each stream's y through LDS; fully-coalesced stores ----
  {
    float* KlF = (float*)Kl;   // 8192 floats = one stream's [r=128][f=64] tile
    const size_t obase = ((size_t)bI * 128 * 400 + (size_t)tI) * 64;
    #pragma unroll
    for (int srnd = 0; srnd < 2; ++srnd) {
      if (wn == srnd) {
        #pragma unroll
        for (int mi = 0; mi < 2; ++mi)
          #pragma unroll
          for (int ni = 0; ni < 4; ++ni) {
            int f = ni*16 + row16;
            #pragma unroll
            for (int j = 0; j < 4; ++j) {
              int r = m0 + mi*16 + q4*4 + j;
              KlF[r*64 + f] = acc[mi][ni][j];
            }
          }
      }
      __syncthreads();
      float* outs = out + (size_t)srnd * 13107200u + obase;
      #pragma unroll
      for (int k = 0; k < 4; ++k) {
        int s = k*512 + tid;              // dwordx4 slot 0..2047
        int r = s >> 4, f4 = (s & 15) * 4;
        float4 v = *(const float4*)(KlF + r*64 + f4);
        *(float4*)(outs + (size_t)r * 25600 + f4) = v;   // 16 lanes = full 256-B row
      }
      if (srnd == 0) __syncthreads();     // stream-1 staging overwrites KlF
    }
  }
}

extern "C" void kernel_launch(void* const* d_in, const int* in_sizes, int n_in,
                              void* d_out, int out_size, void* d_ws, size_t ws_size,
                              hipStream_t stream)
{
  (void)in_sizes; (void)n_in; (void)out_size; (void)ws_size;
  const float* x1 = (const float*)d_in[0];
  const float* x2 = (const float*)d_in[1];
  const float* Wq = (const float*)d_in[2];
  const float* bq = (const float*)d_in[3];
  const float* pq = (const float*)d_in[4];
  const float* gq = (const float*)d_in[5];
  const float* zq = (const float*)d_in[6];
  const float* Wk = (const float*)d_in[7];
  const float* bk = (const float*)d_in[8];
  const float* pk = (const float*)d_in[9];
  const float* gk = (const float*)d_in[10];
  const float* zk = (const float*)d_in[11];
  const float* Wv = (const float*)d_in[12];
  const float* bv = (const float*)d_in[13];
  const float* pv = (const float*)d_in[14];
  const float* gv = (const float*)d_in[15];
  const float* zv = (const float*)d_in[16];
  const float* Wo = (const float*)d_in[17];
  const float* bo = (const float*)d_in[18];
  const float* po = (const float*)d_in[19];
  const float* go = (const float*)d_in[20];
  const float* zo = (const float*)d_in[21];

  unsigned short* Wb = (unsigned short*)d_ws;             // hi: 131072 B, lo: 131072 B
  unsigned*       GZ = (unsigned*)((char*)d_ws + 262144); // 131072 B

  prep_k<<<384, 256, 0, stream>>>(Wq, Wk, Wv, Wo, gq, zq, gk, zk, gv, zv, go, zo, Wb, GZ);
  fused_k<<<1600, 512, 0, stream>>>(x1, x2, Wb, GZ, bq, bk, bv, bo, pq, pk, pv, po,
                                    (float*)d_out);
}